// Round 1
// baseline (172.656 us; speedup 1.0000x reference)
//
#include <hip/hip_runtime.h>
#include <hip/hip_bf16.h>
#include <stdint.h>

typedef unsigned int u32;
typedef unsigned short u16;
typedef __attribute__((ext_vector_type(8))) short short8;   // 8 bf16 (MFMA A/B frag)
typedef __attribute__((ext_vector_type(4))) float floatx4;  // MFMA C/D frag

#define N_DIM 1024       // ROW*Y_ROW (output features)
#define K_DIM 1024       // COL*Z_COL (input features)
#define M_DIM 16384      // BATCH*SEQ
#define EPW  68          // epilogue LDS row stride in words (64 fp32 + 4 pad)

__device__ __forceinline__ u32 pack4(uint4 v) {
    return (v.x & 0xffu) | ((v.y & 0xffu) << 8) | ((v.z & 0xffu) << 16) | (v.w << 24);
}

__device__ __forceinline__ u16 bf16rne(float f) {
    u32 u = __float_as_uint(f);
    return (u16)((u + 0x7fffu + ((u >> 16) & 1u)) >> 16);
}

// async global->LDS, 16B per lane. LDS dest must be wave-uniform base + lane*16.
__device__ __forceinline__ void load16_lds(const void* g, void* l) {
    __builtin_amdgcn_global_load_lds(
        (const __attribute__((address_space(1))) void*)g,
        (__attribute__((address_space(3))) void*)l, 16, 0, 0);
}

// ---------------------------------------------------------------------------
// build_w: W[n,k] (bf16, row-major [N_DIM][K_DIM], n=r*128+y, k=c*128+z)
//   = d + sum_bit( a*popcnt(Y&Z) + b*Ysum + c*Zsum )
// Uniform runtime detection of uint8 vs int32-widened packed inputs.
// Grid: 256 blocks = (r,c) x z-quarter, 256 threads.
// ---------------------------------------------------------------------------
__global__ __launch_bounds__(256) void build_w(
        const u32* __restrict__ yp, const u32* __restrict__ zp,
        const int* __restrict__ ysum, const int* __restrict__ zsum,
        const float* __restrict__ pa, const float* __restrict__ pb,
        const float* __restrict__ pc, const float* __restrict__ pd,
        __hip_bfloat16* __restrict__ Wb) {
    __shared__ u32 sY[4096];   // [bit][y][t] words (16 KiB)
    __shared__ u32 sZ[1024];   // [bit][zl][t] words (4 KiB)
    __shared__ int sYs[512];
    __shared__ int sZs[128];

    const int tid = threadIdx.x;
    const int rc = blockIdx.x >> 2;
    const int zq = blockIdx.x & 3;
    const int r = rc >> 3, c = rc & 7;
    const int z0 = zq * 32;

    // uniform mode detect (32 logical bytes vs Y_sum[0])
    const uint4 d0 = ((const uint4*)yp)[0], d1 = ((const uint4*)yp)[1];
    const int sdet = __popc(d0.x) + __popc(d0.y) + __popc(d0.z) + __popc(d0.w)
                   + __popc(d1.x) + __popc(d1.y) + __popc(d1.z) + __popc(d1.w);
    const bool widened = (sdet != ysum[0]);

    if (!widened) {
#pragma unroll
        for (int j = 0; j < 4; ++j) {
            const int chunk = tid + j * 256;
            const int f = chunk * 4;                    // logical word id in block
            const int bit = f >> 10, rem = f & 1023;
            const u32 gw = (u32)((bit * 64 + r * 8 + c) * 1024 + rem);
            ((uint4*)sY)[chunk] = *(const uint4*)(yp + gw);
        }
        {
            const int f = tid * 4;
            const int bit = f >> 8;
            const u32 gw = (u32)((bit * 64 + r * 8 + c) * 1024 + z0 * 8 + (f & 255));
            ((uint4*)sZ)[tid] = *(const uint4*)(zp + gw);
        }
    } else {
#pragma unroll
        for (int j = 0; j < 4; ++j) {
            const int chunk = tid + j * 256;
            const int f = chunk * 4;
            const int bit = f >> 10, rem = f & 1023;
            const u32 gw = (u32)((bit * 64 + r * 8 + c) * 1024 + rem);
            uint4 o;
            o.x = pack4(((const uint4*)yp)[gw + 0]);
            o.y = pack4(((const uint4*)yp)[gw + 1]);
            o.z = pack4(((const uint4*)yp)[gw + 2]);
            o.w = pack4(((const uint4*)yp)[gw + 3]);
            ((uint4*)sY)[chunk] = o;
        }
        {
            const int f = tid * 4;
            const int bit = f >> 8;
            const u32 gw = (u32)((bit * 64 + r * 8 + c) * 1024 + z0 * 8 + (f & 255));
            uint4 o;
            o.x = pack4(((const uint4*)zp)[gw + 0]);
            o.y = pack4(((const uint4*)zp)[gw + 1]);
            o.z = pack4(((const uint4*)zp)[gw + 2]);
            o.w = pack4(((const uint4*)zp)[gw + 3]);
            ((uint4*)sZ)[tid] = o;
        }
    }
    for (int j = tid; j < 512; j += 256) {
        const int bit = j >> 7, y = j & 127;
        sYs[j] = ysum[((bit * 8 + r) * 8 + c) * 128 + y];
    }
    if (tid < 128) {
        const int bit = tid >> 5, zl = tid & 31;
        sZs[tid] = zsum[((bit * 8 + r) * 8 + c) * 128 + z0 + zl];
    }
    __syncthreads();

    float av[4], bv[4], cv[4];
#pragma unroll
    for (int bit = 0; bit < 4; ++bit) { av[bit] = pa[bit]; bv[bit] = pb[bit]; cv[bit] = pc[bit]; }
    const float dv = pd[0];

    const int y = tid & 127;
    const int zh = tid >> 7;       // 0/1 -> 16 z each

    u32 yw[4][8];
    float base = dv;
#pragma unroll
    for (int bit = 0; bit < 4; ++bit) {
        const uint4 q0 = ((const uint4*)sY)[bit * 256 + y * 2];
        const uint4 q1 = ((const uint4*)sY)[bit * 256 + y * 2 + 1];
        yw[bit][0] = q0.x; yw[bit][1] = q0.y; yw[bit][2] = q0.z; yw[bit][3] = q0.w;
        yw[bit][4] = q1.x; yw[bit][5] = q1.y; yw[bit][6] = q1.z; yw[bit][7] = q1.w;
        base += bv[bit] * (float)sYs[bit * 128 + y];
    }

    const int m = r * 128 + y;
#pragma unroll
    for (int zl2 = 0; zl2 < 16; ++zl2) {
        const int zl = zh * 16 + zl2;
        float wv = base;
#pragma unroll
        for (int bit = 0; bit < 4; ++bit) {
            const uint4 zw0 = ((const uint4*)sZ)[bit * 64 + zl * 2];
            const uint4 zw1 = ((const uint4*)sZ)[bit * 64 + zl * 2 + 1];
            int p = 0;
            p += __popc(yw[bit][0] & zw0.x);
            p += __popc(yw[bit][1] & zw0.y);
            p += __popc(yw[bit][2] & zw0.z);
            p += __popc(yw[bit][3] & zw0.w);
            p += __popc(yw[bit][4] & zw1.x);
            p += __popc(yw[bit][5] & zw1.y);
            p += __popc(yw[bit][6] & zw1.z);
            p += __popc(yw[bit][7] & zw1.w);
            wv += av[bit] * (float)p + cv[bit] * (float)sZs[bit * 32 + zl];
        }
        const int k = c * 128 + z0 + zl;
        Wb[(size_t)m * K_DIM + k] = __float2bfloat16(wv);
    }
}

// ---------------------------------------------------------------------------
// convert_x: X fp32 [16384][1024] -> bf16 (RNE). 8192 blocks x 256 threads,
// 2 float4 per thread, fully coalesced.
// ---------------------------------------------------------------------------
__global__ __launch_bounds__(256) void convert_x(const float4* __restrict__ X,
                                                 ushort4* __restrict__ Xb) {
    const size_t base = (size_t)blockIdx.x * 512;
    const int tid = threadIdx.x;
    const float4 a = X[base + tid];
    const float4 b = X[base + 256 + tid];
    ushort4 oa, ob;
    oa.x = bf16rne(a.x); oa.y = bf16rne(a.y); oa.z = bf16rne(a.z); oa.w = bf16rne(a.w);
    ob.x = bf16rne(b.x); ob.y = bf16rne(b.y); ob.z = bf16rne(b.z); ob.w = bf16rne(b.w);
    Xb[base + tid] = oa;
    Xb[base + 256 + tid] = ob;
}

// ---------------------------------------------------------------------------
// gemm_bias: out[M,N] = Xb[M,K] * Wb[N,K]^T + bias[N]   (bf16 MFMA, fp32 out)
//
// 256(M) x 256(N) tile, BK=64, 512 threads = 8 waves (2M x 4N), per-wave
// output 128x64. Double-buffered LDS: 2 slots x (A 32K + B 32K) = 128 KiB
// (dynamic). Counted-vmcnt pipeline (T3+T4): stage(kt+2) is issued into the
// slot freed by kt's last read; main-loop wait is vmcnt(8) -- never 0 -- so
// the next tile's 8 loads stay in flight across the raw s_barriers.
// Chunk-XOR swizzle (proven in prior version): 16B chunk (row,kc) stored at
// chunk index kc^(row&7) via pre-swizzled global source + linear LDS dest;
// reads use byte col ((kk*4+fq)^(fm&7))*16.
// Grid dim3(64,4): x = mtile -> XCD = mtile%8 (64*y === 0 mod 8), so the 4
// ntile-blocks sharing an A-panel are co-resident on one XCD -> A from L2.
// ---------------------------------------------------------------------------
__global__ __launch_bounds__(512, 2) void gemm_bias(
        const u16* __restrict__ Xb, const u16* __restrict__ Wb,
        const float* __restrict__ bias, float* __restrict__ out) {
    extern __shared__ char lds[];    // 131072 B: slot s at s*65536 (A), +32768 (B)

    const int tid = threadIdx.x;
    const int lane = tid & 63;
    const int w = tid >> 6;          // wave 0..7
    const int wr = w >> 2;           // 0..1 (M)
    const int wc = w & 3;            // 0..3 (N)
    const int m0 = blockIdx.x * 256;
    const int n0 = blockIdx.y * 256;

    // staging lane decomposition: 64 lanes cover 8 rows x 8 chunks
    const int lrow = lane >> 3;                  // 0..7
    const int lkc  = (lane & 7) ^ lrow;          // swizzled source 16B-chunk
    // fragment lanes
    const int fm = lane & 15, fq = lane >> 4;
    const int cx0 = ((0 + fq) ^ (fm & 7)) * 16;  // kk=0 swizzled byte col
    const int cx1 = ((4 + fq) ^ (fm & 7)) * 16;  // kk=1

    // stage one K-tile (A 256x64 + B 256x64 bf16) into slot s: 8 loads/thread
#define STAGE(kt, s) do {                                                      \
    char* As_ = lds + (s) * 65536;                                             \
    char* Bs_ = lds + (s) * 65536 + 32768;                                     \
    _Pragma("unroll")                                                          \
    for (int j = 0; j < 4; ++j) {                                              \
        const int cw = j * 8 + w;                /* chunk-group 0..31 */       \
        const int row = cw * 8 + lrow;           /* 0..255 */                  \
        load16_lds(Xb + (size_t)(m0 + row) * K_DIM + (kt) * 64 + lkc * 8,      \
                   As_ + cw * 1024 + lane * 16);                               \
    }                                                                          \
    _Pragma("unroll")                                                          \
    for (int j = 0; j < 4; ++j) {                                              \
        const int cw = j * 8 + w;                                              \
        const int row = cw * 8 + lrow;           /* 0..255 */                  \
        load16_lds(Wb + (size_t)(n0 + row) * K_DIM + (kt) * 64 + lkc * 8,      \
                   Bs_ + cw * 1024 + lane * 16);                               \
    }                                                                          \
} while (0)

    floatx4 acc[8][4] = {};

    STAGE(0, 0);
    STAGE(1, 1);

    for (int kt = 0; kt < 16; ++kt) {
        const int s = kt & 1;
        // own loads for kt landed (stage(kt+1)'s 8 may stay in flight);
        // barrier extends the guarantee to all waves' loads.
        if (kt < 15) asm volatile("s_waitcnt vmcnt(8)" ::: "memory");
        else         asm volatile("s_waitcnt vmcnt(0)" ::: "memory");
        __builtin_amdgcn_s_barrier();
        asm volatile("" ::: "memory");

        const char* Ab = lds + s * 65536;
        const char* Bb = lds + s * 65536 + 32768;

        short8 a0[8], b0[4];
#pragma unroll
        for (int mi = 0; mi < 8; ++mi)
            a0[mi] = *(const short8*)(Ab + (wr * 128 + mi * 16 + fm) * 128 + cx0);
#pragma unroll
        for (int ni = 0; ni < 4; ++ni)
            b0[ni] = *(const short8*)(Bb + (wc * 64 + ni * 16 + fm) * 128 + cx0);
#pragma unroll
        for (int mi = 0; mi < 8; ++mi)
#pragma unroll
            for (int ni = 0; ni < 4; ++ni)
                acc[mi][ni] = __builtin_amdgcn_mfma_f32_16x16x32_bf16(
                    a0[mi], b0[ni], acc[mi][ni], 0, 0, 0);

        short8 a1[8], b1[4];
#pragma unroll
        for (int mi = 0; mi < 8; ++mi)
            a1[mi] = *(const short8*)(Ab + (wr * 128 + mi * 16 + fm) * 128 + cx1);
#pragma unroll
        for (int ni = 0; ni < 4; ++ni)
            b1[ni] = *(const short8*)(Bb + (wc * 64 + ni * 16 + fm) * 128 + cx1);
#pragma unroll
        for (int mi = 0; mi < 8; ++mi)
#pragma unroll
            for (int ni = 0; ni < 4; ++ni)
                acc[mi][ni] = __builtin_amdgcn_mfma_f32_16x16x32_bf16(
                    a1[mi], b1[ni], acc[mi][ni], 0, 0, 0);

        // all waves done reading slot s (lgkm drained via MFMA deps) -> safe
        // to issue the overwriting loads; they get a full K-tile to land.
        asm volatile("" ::: "memory");
        __builtin_amdgcn_s_barrier();
        asm volatile("" ::: "memory");
        if (kt < 14) STAGE(kt + 2, s);
    }
#undef STAGE

    // -----------------------------------------------------------------------
    // Epilogue: D layout col(N)=lane&15, row(M)=(lane>>4)*4+reg.
    // Per-wave private LDS slice (16 x EPW fp32) in slot0 region (last K-tile
    // kt=15 read slot1, and all waves passed its top barrier -> slot0 free).
    // -----------------------------------------------------------------------
    float bias_r[4];
#pragma unroll
    for (int ni = 0; ni < 4; ++ni)
        bias_r[ni] = bias[n0 + wc * 64 + ni * 16 + fm];

    __syncthreads();
    float* ep = (float*)lds + w * (16 * EPW);   // 4352 B per wave, 34.8 KB total
    const int gm0 = m0 + wr * 128;
    const int gn0 = n0 + wc * 64;

#pragma unroll
    for (int mi = 0; mi < 8; ++mi) {
#pragma unroll
        for (int ni = 0; ni < 4; ++ni)
#pragma unroll
            for (int reg = 0; reg < 4; ++reg)
                ep[(fq * 4 + reg) * EPW + ni * 16 + fm] = acc[mi][ni][reg] + bias_r[ni];
#pragma unroll
        for (int t = 0; t < 4; ++t) {
            const int lr = t * 4 + fq;               // local row 0..15
            const float4 v = *(const float4*)(ep + lr * EPW + fm * 4);
            *(float4*)(out + (size_t)(gm0 + mi * 16 + lr) * N_DIM + gn0 + fm * 4) = v;
        }
        // wave-private slice; DS pipe is in-order per wave -> WAR safe
    }
}

// ---------------------------------------------------------------------------
extern "C" void kernel_launch(void* const* d_in, const int* in_sizes, int n_in,
                              void* d_out, int out_size, void* d_ws, size_t ws_size,
                              hipStream_t stream) {
    const float* X   = (const float*)d_in[0];
    const u32*   Yp  = (const u32*)d_in[1];
    const u32*   Zp  = (const u32*)d_in[2];
    const int*   Ys  = (const int*)d_in[3];
    const int*   Zs  = (const int*)d_in[4];
    const float* pa  = (const float*)d_in[5];
    const float* pb  = (const float*)d_in[6];
    const float* pc  = (const float*)d_in[7];
    const float* pd  = (const float*)d_in[8];
    const float* bias = (const float*)d_in[9];
    float* out = (float*)d_out;

    char* ws = (char*)d_ws;
    __hip_bfloat16* Wb = (__hip_bfloat16*)ws;                 // 2 MiB
    u16*            Xb = (u16*)(ws + (2u << 20));             // 32 MiB

    static bool attr_set = false;
    if (!attr_set) {
        hipFuncSetAttribute((const void*)gemm_bias,
                            hipFuncAttributeMaxDynamicSharedMemorySize, 131072);
        attr_set = true;
    }

    build_w<<<256, 256, 0, stream>>>(Yp, Zp, Ys, Zs, pa, pb, pc, pd, Wb);
    convert_x<<<8192, 256, 0, stream>>>((const float4*)X, (ushort4*)Xb);
    gemm_bias<<<dim3(64, 4), 512, 131072, stream>>>(Xb, (const u16*)Wb, bias, out);
}

// Round 2
// 169.694 us; speedup vs baseline: 1.0175x; 1.0175x over previous
//
#include <hip/hip_runtime.h>
#include <hip/hip_bf16.h>
#include <stdint.h>

typedef unsigned int u32;
typedef unsigned short u16;
typedef __attribute__((ext_vector_type(8))) short short8;   // 8 bf16 (MFMA A/B frag)
typedef __attribute__((ext_vector_type(4))) float floatx4;  // MFMA C/D frag

#define N_DIM 1024       // ROW*Y_ROW (output features)
#define K_DIM 1024       // COL*Z_COL (input features)
#define M_DIM 16384      // BATCH*SEQ
#define EPW  68          // epilogue LDS row stride in words (64 fp32 + 4 pad)

__device__ __forceinline__ u32 pack4(uint4 v) {
    return (v.x & 0xffu) | ((v.y & 0xffu) << 8) | ((v.z & 0xffu) << 16) | (v.w << 24);
}

__device__ __forceinline__ u16 bf16rne(float f) {
    u32 u = __float_as_uint(f);
    return (u16)((u + 0x7fffu + ((u >> 16) & 1u)) >> 16);
}

// async global->LDS, 16B per lane. LDS dest must be wave-uniform base + lane*16.
__device__ __forceinline__ void load16_lds(const void* g, void* l) {
    __builtin_amdgcn_global_load_lds(
        (const __attribute__((address_space(1))) void*)g,
        (__attribute__((address_space(3))) void*)l, 16, 0, 0);
}

// ---------------------------------------------------------------------------
// prep: merged build_w (blocks 0..255) + convert_x (blocks 256..8447).
// ---------------------------------------------------------------------------
__global__ __launch_bounds__(256) void prep(
        const u32* __restrict__ yp, const u32* __restrict__ zp,
        const int* __restrict__ ysum, const int* __restrict__ zsum,
        const float* __restrict__ pa, const float* __restrict__ pb,
        const float* __restrict__ pc, const float* __restrict__ pd,
        __hip_bfloat16* __restrict__ Wb,
        const float4* __restrict__ X, ushort4* __restrict__ Xb) {
    __shared__ u32 sY[4096];   // [bit][y][t] words (16 KiB)
    __shared__ u32 sZ[1024];   // [bit][zl][t] words (4 KiB)
    __shared__ int sYs[512];
    __shared__ int sZs[128];

    const int tid = threadIdx.x;

    if (blockIdx.x >= 256) {
        // ---- convert_x: X fp32 -> bf16 (RNE), fully coalesced ----
        const size_t base = (size_t)(blockIdx.x - 256) * 512;
        const float4 a = X[base + tid];
        const float4 b = X[base + 256 + tid];
        ushort4 oa, ob;
        oa.x = bf16rne(a.x); oa.y = bf16rne(a.y); oa.z = bf16rne(a.z); oa.w = bf16rne(a.w);
        ob.x = bf16rne(b.x); ob.y = bf16rne(b.y); ob.z = bf16rne(b.z); ob.w = bf16rne(b.w);
        Xb[base + tid] = oa;
        Xb[base + 256 + tid] = ob;
        return;
    }

    // ---- build_w ----
    const int rc = blockIdx.x >> 2;
    const int zq = blockIdx.x & 3;
    const int r = rc >> 3, c = rc & 7;
    const int z0 = zq * 32;

    // uniform mode detect (32 logical bytes vs Y_sum[0])
    const uint4 d0 = ((const uint4*)yp)[0], d1 = ((const uint4*)yp)[1];
    const int sdet = __popc(d0.x) + __popc(d0.y) + __popc(d0.z) + __popc(d0.w)
                   + __popc(d1.x) + __popc(d1.y) + __popc(d1.z) + __popc(d1.w);
    const bool widened = (sdet != ysum[0]);

    if (!widened) {
#pragma unroll
        for (int j = 0; j < 4; ++j) {
            const int chunk = tid + j * 256;
            const int f = chunk * 4;                    // logical word id in block
            const int bit = f >> 10, rem = f & 1023;
            const u32 gw = (u32)((bit * 64 + r * 8 + c) * 1024 + rem);
            ((uint4*)sY)[chunk] = *(const uint4*)(yp + gw);
        }
        {
            const int f = tid * 4;
            const int bit = f >> 8;
            const u32 gw = (u32)((bit * 64 + r * 8 + c) * 1024 + z0 * 8 + (f & 255));
            ((uint4*)sZ)[tid] = *(const uint4*)(zp + gw);
        }
    } else {
#pragma unroll
        for (int j = 0; j < 4; ++j) {
            const int chunk = tid + j * 256;
            const int f = chunk * 4;
            const int bit = f >> 10, rem = f & 1023;
            const u32 gw = (u32)((bit * 64 + r * 8 + c) * 1024 + rem);
            uint4 o;
            o.x = pack4(((const uint4*)yp)[gw + 0]);
            o.y = pack4(((const uint4*)yp)[gw + 1]);
            o.z = pack4(((const uint4*)yp)[gw + 2]);
            o.w = pack4(((const uint4*)yp)[gw + 3]);
            ((uint4*)sY)[chunk] = o;
        }
        {
            const int f = tid * 4;
            const int bit = f >> 8;
            const u32 gw = (u32)((bit * 64 + r * 8 + c) * 1024 + z0 * 8 + (f & 255));
            uint4 o;
            o.x = pack4(((const uint4*)zp)[gw + 0]);
            o.y = pack4(((const uint4*)zp)[gw + 1]);
            o.z = pack4(((const uint4*)zp)[gw + 2]);
            o.w = pack4(((const uint4*)zp)[gw + 3]);
            ((uint4*)sZ)[tid] = o;
        }
    }
    for (int j = tid; j < 512; j += 256) {
        const int bit = j >> 7, y = j & 127;
        sYs[j] = ysum[((bit * 8 + r) * 8 + c) * 128 + y];
    }
    if (tid < 128) {
        const int bit = tid >> 5, zl = tid & 31;
        sZs[tid] = zsum[((bit * 8 + r) * 8 + c) * 128 + z0 + zl];
    }
    __syncthreads();

    float av[4], bv[4], cv[4];
#pragma unroll
    for (int bit = 0; bit < 4; ++bit) { av[bit] = pa[bit]; bv[bit] = pb[bit]; cv[bit] = pc[bit]; }
    const float dv = pd[0];

    const int y = tid & 127;
    const int zh = tid >> 7;       // 0/1 -> 16 z each

    u32 yw[4][8];
    float base = dv;
#pragma unroll
    for (int bit = 0; bit < 4; ++bit) {
        const uint4 q0 = ((const uint4*)sY)[bit * 256 + y * 2];
        const uint4 q1 = ((const uint4*)sY)[bit * 256 + y * 2 + 1];
        yw[bit][0] = q0.x; yw[bit][1] = q0.y; yw[bit][2] = q0.z; yw[bit][3] = q0.w;
        yw[bit][4] = q1.x; yw[bit][5] = q1.y; yw[bit][6] = q1.z; yw[bit][7] = q1.w;
        base += bv[bit] * (float)sYs[bit * 128 + y];
    }

    const int m = r * 128 + y;
#pragma unroll
    for (int zl2 = 0; zl2 < 16; ++zl2) {
        const int zl = zh * 16 + zl2;
        float wv = base;
#pragma unroll
        for (int bit = 0; bit < 4; ++bit) {
            const uint4 zw0 = ((const uint4*)sZ)[bit * 64 + zl * 2];
            const uint4 zw1 = ((const uint4*)sZ)[bit * 64 + zl * 2 + 1];
            int p = 0;
            p += __popc(yw[bit][0] & zw0.x);
            p += __popc(yw[bit][1] & zw0.y);
            p += __popc(yw[bit][2] & zw0.z);
            p += __popc(yw[bit][3] & zw0.w);
            p += __popc(yw[bit][4] & zw1.x);
            p += __popc(yw[bit][5] & zw1.y);
            p += __popc(yw[bit][6] & zw1.z);
            p += __popc(yw[bit][7] & zw1.w);
            wv += av[bit] * (float)p + cv[bit] * (float)sZs[bit * 32 + zl];
        }
        const int k = c * 128 + z0 + zl;
        Wb[(size_t)m * K_DIM + k] = __float2bfloat16(wv);
    }
}

// ---------------------------------------------------------------------------
// gemm_bias: out[M,N] = Xb[M,K] * Wb[N,K]^T + bias[N]   (bf16 MFMA, fp32 out)
//
// 256x256 tile, BK=64, 512 threads = 8 waves (2M x 4N), per-wave 128x64.
// 8-phase schedule (4 phases per K-tile, 2 K-tiles/iter, T3+T4+T5):
//   P1: ds_read A-kk0 (8) + B-kk0 (4); lgkmcnt(8); bar; lgkm0; prio1;
//       16 MFMA (kk0 x ni{0,1}); prio0; bar
//   P2: ds_read B-kk1 (4); bar; lgkm0; prio1; MFMA kk0 x ni{2,3}; prio0; bar
//   P3: ds_read A-kk1 (8); STAGE B(next tile -> this slot); bar; lgkm0;
//       prio1; MFMA kk1 x ni{0,1}; prio0; bar
//   P4: STAGE A(next); vmcnt(8); bar; prio1; MFMA kk1 x ni{2,3}; prio0; bar
// Slot-free proof: slot B last read in P2, A last read in P3 (drained by the
// phase's lgkmcnt(0) before its closing barrier) -> P3/P4 stages are safe.
// vmcnt proof: 4 loads per stage batch; vmcnt(8) leaves only the 2 newest
// batches outstanding -> the tile read in the next 4 phases (staged 4-6
// phases earlier) is landed. Tail iteration: no stage, vmcnt(0) once.
// Grid dim3(64,4): XCD = blockid%8 = mtile%8 -> 4 ntiles share A via L2.
// ---------------------------------------------------------------------------
__device__ __forceinline__ void stage_a(const u16* __restrict__ Xb, int m0, int kt,
                                        char* SB, int w, int lane, int lrow, int lkc) {
#pragma unroll
    for (int j = 0; j < 4; ++j) {
        const int cw = j * 8 + w;                 // chunk-group 0..31
        const int row = cw * 8 + lrow;            // 0..255
        load16_lds(Xb + (size_t)(m0 + row) * K_DIM + kt * 64 + lkc * 8,
                   SB + cw * 1024 + lane * 16);
    }
}
__device__ __forceinline__ void stage_b(const u16* __restrict__ Wb, int n0, int kt,
                                        char* SB, int w, int lane, int lrow, int lkc) {
#pragma unroll
    for (int j = 0; j < 4; ++j) {
        const int cw = j * 8 + w;
        const int row = cw * 8 + lrow;            // 0..255
        load16_lds(Wb + (size_t)(n0 + row) * K_DIM + kt * 64 + lkc * 8,
                   SB + 32768 + cw * 1024 + lane * 16);
    }
}

// VM: 8 -> vmcnt(8) at P4, 0 -> vmcnt(0), -1 -> none (final tile).
template<bool DO_STAGE, int VM>
__device__ __forceinline__ void tile_phases(
        const char* __restrict__ A_, const char* __restrict__ B_, char* SBst, int ktg,
        floatx4 (&acc)[8][4],
        const u16* __restrict__ Xb, const u16* __restrict__ Wb,
        int m0, int n0, int w, int lane, int lrow, int lkc,
        int wr, int wc, int fm, int cx0, int cx1) {
    short8 a0[8], a1[8], b0[4], b1[4];

    // ---- P1: A-kk0 + B-kk0 (12 reads) ----
#pragma unroll
    for (int mi = 0; mi < 8; ++mi)
        a0[mi] = *(const short8*)(A_ + (wr * 128 + mi * 16 + fm) * 128 + cx0);
#pragma unroll
    for (int ni = 0; ni < 4; ++ni)
        b0[ni] = *(const short8*)(B_ + (wc * 64 + ni * 16 + fm) * 128 + cx0);
    asm volatile("s_waitcnt lgkmcnt(8)" ::: "memory");
    __builtin_amdgcn_s_barrier();
    asm volatile("s_waitcnt lgkmcnt(0)" ::: "memory");
    __builtin_amdgcn_s_setprio(1);
#pragma unroll
    for (int mi = 0; mi < 8; ++mi) {
        acc[mi][0] = __builtin_amdgcn_mfma_f32_16x16x32_bf16(a0[mi], b0[0], acc[mi][0], 0, 0, 0);
        acc[mi][1] = __builtin_amdgcn_mfma_f32_16x16x32_bf16(a0[mi], b0[1], acc[mi][1], 0, 0, 0);
    }
    __builtin_amdgcn_s_setprio(0);
    __builtin_amdgcn_s_barrier();

    // ---- P2: B-kk1 (4 reads) ----
#pragma unroll
    for (int ni = 0; ni < 4; ++ni)
        b1[ni] = *(const short8*)(B_ + (wc * 64 + ni * 16 + fm) * 128 + cx1);
    __builtin_amdgcn_s_barrier();
    asm volatile("s_waitcnt lgkmcnt(0)" ::: "memory");
    __builtin_amdgcn_s_setprio(1);
#pragma unroll
    for (int mi = 0; mi < 8; ++mi) {
        acc[mi][2] = __builtin_amdgcn_mfma_f32_16x16x32_bf16(a0[mi], b0[2], acc[mi][2], 0, 0, 0);
        acc[mi][3] = __builtin_amdgcn_mfma_f32_16x16x32_bf16(a0[mi], b0[3], acc[mi][3], 0, 0, 0);
    }
    __builtin_amdgcn_s_setprio(0);
    __builtin_amdgcn_s_barrier();

    // ---- P3: A-kk1 (8 reads); stage next-tile B into this slot ----
#pragma unroll
    for (int mi = 0; mi < 8; ++mi)
        a1[mi] = *(const short8*)(A_ + (wr * 128 + mi * 16 + fm) * 128 + cx1);
    if (DO_STAGE) stage_b(Wb, n0, ktg, SBst, w, lane, lrow, lkc);
    __builtin_amdgcn_s_barrier();
    asm volatile("s_waitcnt lgkmcnt(0)" ::: "memory");
    __builtin_amdgcn_s_setprio(1);
#pragma unroll
    for (int mi = 0; mi < 8; ++mi) {
        acc[mi][0] = __builtin_amdgcn_mfma_f32_16x16x32_bf16(a1[mi], b1[0], acc[mi][0], 0, 0, 0);
        acc[mi][1] = __builtin_amdgcn_mfma_f32_16x16x32_bf16(a1[mi], b1[1], acc[mi][1], 0, 0, 0);
    }
    __builtin_amdgcn_s_setprio(0);
    __builtin_amdgcn_s_barrier();

    // ---- P4: stage next-tile A; counted vmcnt; MFMA kk1 x ni{2,3} ----
    if (DO_STAGE) stage_a(Xb, m0, ktg, SBst, w, lane, lrow, lkc);
    if (VM == 8)      asm volatile("s_waitcnt vmcnt(8)" ::: "memory");
    else if (VM == 0) asm volatile("s_waitcnt vmcnt(0)" ::: "memory");
    __builtin_amdgcn_s_barrier();
    __builtin_amdgcn_s_setprio(1);
#pragma unroll
    for (int mi = 0; mi < 8; ++mi) {
        acc[mi][2] = __builtin_amdgcn_mfma_f32_16x16x32_bf16(a1[mi], b1[2], acc[mi][2], 0, 0, 0);
        acc[mi][3] = __builtin_amdgcn_mfma_f32_16x16x32_bf16(a1[mi], b1[3], acc[mi][3], 0, 0, 0);
    }
    __builtin_amdgcn_s_setprio(0);
    __builtin_amdgcn_s_barrier();
}

__global__ __launch_bounds__(512, 2) void gemm_bias(
        const u16* __restrict__ Xb, const u16* __restrict__ Wb,
        const float* __restrict__ bias, float* __restrict__ out) {
    extern __shared__ char lds[];    // 131072 B: slot0 @0, slot1 @65536 (A then B)

    const int tid = threadIdx.x;
    const int lane = tid & 63;
    const int w = tid >> 6;          // wave 0..7
    const int wr = w >> 2;           // 0..1 (M)
    const int wc = w & 3;            // 0..3 (N)
    const int m0 = blockIdx.x * 256;
    const int n0 = blockIdx.y * 256;

    // staging lane decomposition: 64 lanes cover 8 rows x 8 chunks
    const int lrow = lane >> 3;                  // 0..7
    const int lkc  = (lane & 7) ^ lrow;          // swizzled source 16B-chunk
    // fragment lanes
    const int fm = lane & 15, fq = lane >> 4;
    const int cx0 = ((0 + fq) ^ (fm & 7)) * 16;  // kk=0 swizzled byte col
    const int cx1 = ((4 + fq) ^ (fm & 7)) * 16;  // kk=1

    char* slot0 = lds;
    char* slot1 = lds + 65536;

    floatx4 acc[8][4] = {};

    // prologue: tiles 0 (slot0) and 1 (slot1); force tile0 landed
    stage_b(Wb, n0, 0, slot0, w, lane, lrow, lkc);
    stage_a(Xb, m0, 0, slot0, w, lane, lrow, lkc);
    stage_b(Wb, n0, 1, slot1, w, lane, lrow, lkc);
    stage_a(Xb, m0, 1, slot1, w, lane, lrow, lkc);
    asm volatile("s_waitcnt vmcnt(8)" ::: "memory");
    __builtin_amdgcn_s_barrier();

    // steady iterations: compute tiles (2i, 2i+1), stage tiles (2i+2, 2i+3)
    for (int it = 0; it < 7; ++it) {
        tile_phases<true, 8>(slot0, slot0 + 32768, slot0, 2 * it + 2, acc,
                             Xb, Wb, m0, n0, w, lane, lrow, lkc, wr, wc, fm, cx0, cx1);
        tile_phases<true, 8>(slot1, slot1 + 32768, slot1, 2 * it + 3, acc,
                             Xb, Wb, m0, n0, w, lane, lrow, lkc, wr, wc, fm, cx0, cx1);
    }
    // tail: tiles 14,15 -- no staging; one vmcnt(0) to retire tile 15's loads
    tile_phases<false, 0>(slot0, slot0 + 32768, slot0, 0, acc,
                          Xb, Wb, m0, n0, w, lane, lrow, lkc, wr, wc, fm, cx0, cx1);
    tile_phases<false, -1>(slot1, slot1 + 32768, slot1, 0, acc,
                           Xb, Wb, m0, n0, w, lane, lrow, lkc, wr, wc, fm, cx0, cx1);

    // -----------------------------------------------------------------------
    // Epilogue: D layout col(N)=lane&15, row(M)=(lane>>4)*4+reg.
    // Per-wave private LDS slice (16 x EPW fp32): transpose to row-major,
    // store float4 (256 B contiguous per 16-lane group).
    // -----------------------------------------------------------------------
    float bias_r[4];
#pragma unroll
    for (int ni = 0; ni < 4; ++ni)
        bias_r[ni] = bias[n0 + wc * 64 + ni * 16 + fm];

    __syncthreads();   // all waves done with both slots; no stage loads pending
    float* ep = (float*)lds + w * (16 * EPW);   // 4352 B per wave, 34.8 KB total
    const int gm0 = m0 + wr * 128;
    const int gn0 = n0 + wc * 64;

#pragma unroll
    for (int mi = 0; mi < 8; ++mi) {
#pragma unroll
        for (int ni = 0; ni < 4; ++ni)
#pragma unroll
            for (int reg = 0; reg < 4; ++reg)
                ep[(fq * 4 + reg) * EPW + ni * 16 + fm] = acc[mi][ni][reg] + bias_r[ni];
#pragma unroll
        for (int t = 0; t < 4; ++t) {
            const int lr = t * 4 + fq;               // local row 0..15
            const float4 v = *(const float4*)(ep + lr * EPW + fm * 4);
            *(float4*)(out + (size_t)(gm0 + mi * 16 + lr) * N_DIM + gn0 + fm * 4) = v;
        }
        // wave-private slice; DS pipe is in-order per wave -> WAR safe
    }
}

// ---------------------------------------------------------------------------
extern "C" void kernel_launch(void* const* d_in, const int* in_sizes, int n_in,
                              void* d_out, int out_size, void* d_ws, size_t ws_size,
                              hipStream_t stream) {
    const float* X   = (const float*)d_in[0];
    const u32*   Yp  = (const u32*)d_in[1];
    const u32*   Zp  = (const u32*)d_in[2];
    const int*   Ys  = (const int*)d_in[3];
    const int*   Zs  = (const int*)d_in[4];
    const float* pa  = (const float*)d_in[5];
    const float* pb  = (const float*)d_in[6];
    const float* pc  = (const float*)d_in[7];
    const float* pd  = (const float*)d_in[8];
    const float* bias = (const float*)d_in[9];
    float* out = (float*)d_out;

    char* ws = (char*)d_ws;
    __hip_bfloat16* Wb = (__hip_bfloat16*)ws;                 // 2 MiB
    u16*            Xb = (u16*)(ws + (2u << 20));             // 32 MiB

    static bool attr_set = false;
    if (!attr_set) {
        hipFuncSetAttribute((const void*)gemm_bias,
                            hipFuncAttributeMaxDynamicSharedMemorySize, 131072);
        attr_set = true;
    }

    prep<<<8448, 256, 0, stream>>>(Yp, Zp, Ys, Zs, pa, pb, pc, pd, Wb,
                                   (const float4*)X, (ushort4*)Xb);
    gemm_bias<<<dim3(64, 4), 512, 131072, stream>>>(Xb, (const u16*)Wb, bias, out);
}

// Round 5
// 169.648 us; speedup vs baseline: 1.0177x; 1.0003x over previous
//
#include <hip/hip_runtime.h>
#include <hip/hip_bf16.h>
#include <stdint.h>

typedef unsigned int u32;
typedef unsigned short u16;
typedef __attribute__((ext_vector_type(8))) short short8;   // 8 bf16 (MFMA A/B frag)
typedef __attribute__((ext_vector_type(4))) float floatx4;  // MFMA C/D frag

#define N_DIM 1024       // ROW*Y_ROW (output features)
#define K_DIM 1024       // COL*Z_COL (input features)
#define M_DIM 16384      // BATCH*SEQ
#define EPW  68          // epilogue LDS row stride in words (64 fp32 + 4 pad)

__device__ __forceinline__ u32 pack4(uint4 v) {
    return (v.x & 0xffu) | ((v.y & 0xffu) << 8) | ((v.z & 0xffu) << 16) | (v.w << 24);
}

__device__ __forceinline__ u16 bf16rne(float f) {
    u32 u = __float_as_uint(f);
    return (u16)((u + 0x7fffu + ((u >> 16) & 1u)) >> 16);
}

// async global->LDS, 16B per lane. LDS dest must be wave-uniform base + lane*16.
__device__ __forceinline__ void load16_lds(const void* g, void* l) {
    __builtin_amdgcn_global_load_lds(
        (const __attribute__((address_space(1))) void*)g,
        (__attribute__((address_space(3))) void*)l, 16, 0, 0);
}

// ---------------------------------------------------------------------------
// prep: merged build_w (blocks 0..255) + convert_x (blocks 256..8447).
// ---------------------------------------------------------------------------
__global__ __launch_bounds__(256) void prep(
        const u32* __restrict__ yp, const u32* __restrict__ zp,
        const int* __restrict__ ysum, const int* __restrict__ zsum,
        const float* __restrict__ pa, const float* __restrict__ pb,
        const float* __restrict__ pc, const float* __restrict__ pd,
        __hip_bfloat16* __restrict__ Wb,
        const float4* __restrict__ X, ushort4* __restrict__ Xb) {
    __shared__ u32 sY[4096];   // [bit][y][t] words (16 KiB)
    __shared__ u32 sZ[1024];   // [bit][zl][t] words (4 KiB)
    __shared__ int sYs[512];
    __shared__ int sZs[128];

    const int tid = threadIdx.x;

    if (blockIdx.x >= 256) {
        // ---- convert_x: X fp32 -> bf16 (RNE), fully coalesced ----
        const size_t base = (size_t)(blockIdx.x - 256) * 512;
        const float4 a = X[base + tid];
        const float4 b = X[base + 256 + tid];
        ushort4 oa, ob;
        oa.x = bf16rne(a.x); oa.y = bf16rne(a.y); oa.z = bf16rne(a.z); oa.w = bf16rne(a.w);
        ob.x = bf16rne(b.x); ob.y = bf16rne(b.y); ob.z = bf16rne(b.z); ob.w = bf16rne(b.w);
        Xb[base + tid] = oa;
        Xb[base + 256 + tid] = ob;
        return;
    }

    // ---- build_w ----
    const int rc = blockIdx.x >> 2;
    const int zq = blockIdx.x & 3;
    const int r = rc >> 3, c = rc & 7;
    const int z0 = zq * 32;

    // uniform mode detect (32 logical bytes vs Y_sum[0])
    const uint4 d0 = ((const uint4*)yp)[0], d1 = ((const uint4*)yp)[1];
    const int sdet = __popc(d0.x) + __popc(d0.y) + __popc(d0.z) + __popc(d0.w)
                   + __popc(d1.x) + __popc(d1.y) + __popc(d1.z) + __popc(d1.w);
    const bool widened = (sdet != ysum[0]);

    if (!widened) {
#pragma unroll
        for (int j = 0; j < 4; ++j) {
            const int chunk = tid + j * 256;
            const int f = chunk * 4;                    // logical word id in block
            const int bit = f >> 10, rem = f & 1023;
            const u32 gw = (u32)((bit * 64 + r * 8 + c) * 1024 + rem);
            ((uint4*)sY)[chunk] = *(const uint4*)(yp + gw);
        }
        {
            const int f = tid * 4;
            const int bit = f >> 8;
            const u32 gw = (u32)((bit * 64 + r * 8 + c) * 1024 + z0 * 8 + (f & 255));
            ((uint4*)sZ)[tid] = *(const uint4*)(zp + gw);
        }
    } else {
#pragma unroll
        for (int j = 0; j < 4; ++j) {
            const int chunk = tid + j * 256;
            const int f = chunk * 4;
            const int bit = f >> 10, rem = f & 1023;
            const u32 gw = (u32)((bit * 64 + r * 8 + c) * 1024 + rem);
            uint4 o;
            o.x = pack4(((const uint4*)yp)[gw + 0]);
            o.y = pack4(((const uint4*)yp)[gw + 1]);
            o.z = pack4(((const uint4*)yp)[gw + 2]);
            o.w = pack4(((const uint4*)yp)[gw + 3]);
            ((uint4*)sY)[chunk] = o;
        }
        {
            const int f = tid * 4;
            const int bit = f >> 8;
            const u32 gw = (u32)((bit * 64 + r * 8 + c) * 1024 + z0 * 8 + (f & 255));
            uint4 o;
            o.x = pack4(((const uint4*)zp)[gw + 0]);
            o.y = pack4(((const uint4*)zp)[gw + 1]);
            o.z = pack4(((const uint4*)zp)[gw + 2]);
            o.w = pack4(((const uint4*)zp)[gw + 3]);
            ((uint4*)sZ)[tid] = o;
        }
    }
    for (int j = tid; j < 512; j += 256) {
        const int bit = j >> 7, y = j & 127;
        sYs[j] = ysum[((bit * 8 + r) * 8 + c) * 128 + y];
    }
    if (tid < 128) {
        const int bit = tid >> 5, zl = tid & 31;
        sZs[tid] = zsum[((bit * 8 + r) * 8 + c) * 128 + z0 + zl];
    }
    __syncthreads();

    float av[4], bv[4], cv[4];
#pragma unroll
    for (int bit = 0; bit < 4; ++bit) { av[bit] = pa[bit]; bv[bit] = pb[bit]; cv[bit] = pc[bit]; }
    const float dv = pd[0];

    const int y = tid & 127;
    const int zh = tid >> 7;       // 0/1 -> 16 z each

    u32 yw[4][8];
    float base = dv;
#pragma unroll
    for (int bit = 0; bit < 4; ++bit) {
        const uint4 q0 = ((const uint4*)sY)[bit * 256 + y * 2];
        const uint4 q1 = ((const uint4*)sY)[bit * 256 + y * 2 + 1];
        yw[bit][0] = q0.x; yw[bit][1] = q0.y; yw[bit][2] = q0.z; yw[bit][3] = q0.w;
        yw[bit][4] = q1.x; yw[bit][5] = q1.y; yw[bit][6] = q1.z; yw[bit][7] = q1.w;
        base += bv[bit] * (float)sYs[bit * 128 + y];
    }

    const int m = r * 128 + y;
#pragma unroll
    for (int zl2 = 0; zl2 < 16; ++zl2) {
        const int zl = zh * 16 + zl2;
        float wv = base;
#pragma unroll
        for (int bit = 0; bit < 4; ++bit) {
            const uint4 zw0 = ((const uint4*)sZ)[bit * 64 + zl * 2];
            const uint4 zw1 = ((const uint4*)sZ)[bit * 64 + zl * 2 + 1];
            int p = 0;
            p += __popc(yw[bit][0] & zw0.x);
            p += __popc(yw[bit][1] & zw0.y);
            p += __popc(yw[bit][2] & zw0.z);
            p += __popc(yw[bit][3] & zw0.w);
            p += __popc(yw[bit][4] & zw1.x);
            p += __popc(yw[bit][5] & zw1.y);
            p += __popc(yw[bit][6] & zw1.z);
            p += __popc(yw[bit][7] & zw1.w);
            wv += av[bit] * (float)p + cv[bit] * (float)sZs[bit * 32 + zl];
        }
        const int k = c * 128 + z0 + zl;
        Wb[(size_t)m * K_DIM + k] = __float2bfloat16(wv);
    }
}

// ---------------------------------------------------------------------------
// gemm_bias: out[M,N] = Xb[M,K] * Wb[N,K]^T + bias[N]   (bf16 MFMA, fp32 out)
//
// 256(M) x 128(N) tile, BK=32, 256 threads = 4 waves (2M x 2N), per-wave
// 128x64. Double-buffered LDS 2 x 24 KB = 48 KB static -> 2 blocks/CU.
// Co-resident blocks (x,y) and (x,y+4) share the A panel (L2-hot) and cover
// each other's barrier/prologue/epilogue stalls.
// Per K-tile (2 phases):
//   P1: 12 ds_read_b128 (a[0..7], b[0..3]); bar; lgkmcnt(0); prio1;
//       16 MFMA (ni 0,1); prio0; bar
//   P2: STAGE(t+2) (6 global_load_lds); vmcnt(6); bar; prio1;
//       16 MFMA (ni 2,3); prio0; bar
// Safety: lgkm0 before P1's closing barrier drains ALL 12 reads (incl. the
// b[2]/b[3] not consumed until P2) -> P2's overwriting stage is WAR-safe.
// vmcnt ledger (prologue fully drains via __syncthreads): at tile t's P2
// after staging batch(t+2), outstanding <= batch(t+1)+batch(t+2) = 12;
// vmcnt(6) retires batch(t+1), needed by tile t+1's P1; closing barrier
// extends to all waves. Tail tiles 30,31: no stage, vmcnt(0) (2nd = no-op).
// BK=32 swizzle: 1-KB slab = 16 rows x 4 chunks(16B); store chunk
// (l&3)^((l>>3)&3) (= (row>>1)&3 row-constant XOR, bijective) via per-lane
// global source; read byte col (fq^((fm>>1)&3))*16 (verified: slot s of row
// r holds source chunk s^((r>>1)&3), so chunk fq is at slot fq^((fm>>1)&3);
// byte addr R*64+cx).
// Grid dim3(64,8): XCD = x%8 -> all 8 ntiles of an mtile on one XCD.
// ---------------------------------------------------------------------------
__device__ __forceinline__ void stage32(const u16* __restrict__ Xb,
        const u16* __restrict__ Wb, int m0, int n0, int kt, char* slot,
        int w, int lane, int srow, int csrc) {
#pragma unroll
    for (int j = 0; j < 4; ++j) {
        const int slab = w * 4 + j;               // 0..15
        const int row = slab * 16 + srow;         // 0..255
        load16_lds(Xb + (size_t)(m0 + row) * K_DIM + kt * 32 + csrc * 8,
                   slot + slab * 1024 + lane * 16);
    }
#pragma unroll
    for (int j = 0; j < 2; ++j) {
        const int slab = w * 2 + j;               // 0..7
        const int row = slab * 16 + srow;         // 0..127
        load16_lds(Wb + (size_t)(n0 + row) * K_DIM + kt * 32 + csrc * 8,
                   slot + 16384 + slab * 1024 + lane * 16);
    }
}

// VM: 6 -> vmcnt(6) steady; 0 -> vmcnt(0) (tail tiles).
template<bool DO_STAGE, int VM>
__device__ __forceinline__ void tile32(const char* __restrict__ slot,
        char* stslot, int ktg, floatx4 (&acc)[8][4],
        const u16* __restrict__ Xb, const u16* __restrict__ Wb,
        int m0, int n0, int w, int lane, int srow, int csrc,
        int wr, int wc, int fm, int cx) {
    const char* As = slot;
    const char* Bs = slot + 16384;
    short8 a[8], b[4];

    // ---- P1 ----
#pragma unroll
    for (int mi = 0; mi < 8; ++mi)
        a[mi] = *(const short8*)(As + (wr * 128 + mi * 16 + fm) * 64 + cx);
#pragma unroll
    for (int ni = 0; ni < 4; ++ni)
        b[ni] = *(const short8*)(Bs + (wc * 64 + ni * 16 + fm) * 64 + cx);
    __builtin_amdgcn_s_barrier();
    asm volatile("s_waitcnt lgkmcnt(0)" ::: "memory");
    __builtin_amdgcn_s_setprio(1);
#pragma unroll
    for (int mi = 0; mi < 8; ++mi) {
        acc[mi][0] = __builtin_amdgcn_mfma_f32_16x16x32_bf16(a[mi], b[0], acc[mi][0], 0, 0, 0);
        acc[mi][1] = __builtin_amdgcn_mfma_f32_16x16x32_bf16(a[mi], b[1], acc[mi][1], 0, 0, 0);
    }
    __builtin_amdgcn_s_setprio(0);
    __builtin_amdgcn_s_barrier();

    // ---- P2 ----
    if (DO_STAGE) stage32(Xb, Wb, m0, n0, ktg, stslot, w, lane, srow, csrc);
    if (VM == 6)      asm volatile("s_waitcnt vmcnt(6)" ::: "memory");
    else              asm volatile("s_waitcnt vmcnt(0)" ::: "memory");
    __builtin_amdgcn_s_barrier();
    __builtin_amdgcn_s_setprio(1);
#pragma unroll
    for (int mi = 0; mi < 8; ++mi) {
        acc[mi][2] = __builtin_amdgcn_mfma_f32_16x16x32_bf16(a[mi], b[2], acc[mi][2], 0, 0, 0);
        acc[mi][3] = __builtin_amdgcn_mfma_f32_16x16x32_bf16(a[mi], b[3], acc[mi][3], 0, 0, 0);
    }
    __builtin_amdgcn_s_setprio(0);
    __builtin_amdgcn_s_barrier();
}

__global__ __launch_bounds__(256, 2) void gemm_bias(
        const u16* __restrict__ Xb, const u16* __restrict__ Wb,
        const float* __restrict__ bias, float* __restrict__ out) {
    __shared__ char lds[49152];    // slot s at s*24576: A[256][32] then B[128][32]

    const int tid = threadIdx.x;
    const int lane = tid & 63;
    const int w = tid >> 6;          // wave 0..3
    const int wr = w >> 1;           // 0..1 (M)
    const int wc = w & 1;            // 0..1 (N)
    const int m0 = blockIdx.x * 256;
    const int n0 = blockIdx.y * 128;

    // staging lane decomposition: 64 lanes cover one 1-KB slab = 16 rows x 4 chunks
    const int srow = lane >> 2;                        // 0..15
    const int csrc = (lane & 3) ^ ((lane >> 3) & 3);   // swizzled source chunk
    // fragment lanes
    const int fm = lane & 15, fq = lane >> 4;
    const int cx = (fq ^ ((fm >> 1) & 3)) * 16;        // swizzled byte col

    char* slot0 = lds;
    char* slot1 = lds + 24576;

    floatx4 acc[8][4] = {};

    // prologue: tiles 0 (slot0), 1 (slot1); full drain + barrier (once).
    stage32(Xb, Wb, m0, n0, 0, slot0, w, lane, srow, csrc);
    stage32(Xb, Wb, m0, n0, 1, slot1, w, lane, srow, csrc);
    __syncthreads();   // drains vmcnt to 0; both prologue tiles resident

    for (int it = 0; it < 15; ++it) {
        tile32<true, 6>(slot0, slot0, 2 * it + 2, acc, Xb, Wb, m0, n0,
                        w, lane, srow, csrc, wr, wc, fm, cx);
        tile32<true, 6>(slot1, slot1, 2 * it + 3, acc, Xb, Wb, m0, n0,
                        w, lane, srow, csrc, wr, wc, fm, cx);
    }
    // tail: tiles 30, 31 -- no staging, conservative full drains
    tile32<false, 0>(slot0, slot0, 0, acc, Xb, Wb, m0, n0,
                     w, lane, srow, csrc, wr, wc, fm, cx);
    tile32<false, 0>(slot1, slot1, 0, acc, Xb, Wb, m0, n0,
                     w, lane, srow, csrc, wr, wc, fm, cx);

    // -----------------------------------------------------------------------
    // Epilogue: D layout col(N)=lane&15, row(M)=(lane>>4)*4+reg.
    // Per-wave private LDS slice (16 x EPW fp32): transpose to row-major,
    // store float4 (256 B contiguous per 16-lane group).
    // -----------------------------------------------------------------------
    float bias_r[4];
#pragma unroll
    for (int ni = 0; ni < 4; ++ni)
        bias_r[ni] = bias[n0 + wc * 64 + ni * 16 + fm];

    __syncthreads();   // all waves done with both slots; no vm loads pending
    float* ep = (float*)lds + w * (16 * EPW);   // 4352 B per wave, 17.4 KB total
    const int gm0 = m0 + wr * 128;
    const int gn0 = n0 + wc * 64;

#pragma unroll
    for (int mi = 0; mi < 8; ++mi) {
#pragma unroll
        for (int ni = 0; ni < 4; ++ni)
#pragma unroll
            for (int reg = 0; reg < 4; ++reg)
                ep[(fq * 4 + reg) * EPW + ni * 16 + fm] = acc[mi][ni][reg] + bias_r[ni];
#pragma unroll
        for (int t = 0; t < 4; ++t) {
            const int lr = t * 4 + fq;               // local row 0..15
            const float4 v = *(const float4*)(ep + lr * EPW + fm * 4);
            *(float4*)(out + (size_t)(gm0 + mi * 16 + lr) * N_DIM + gn0 + fm * 4) = v;
        }
        // wave-private slice; DS pipe is in-order per wave -> WAR safe
    }
}

// ---------------------------------------------------------------------------
extern "C" void kernel_launch(void* const* d_in, const int* in_sizes, int n_in,
                              void* d_out, int out_size, void* d_ws, size_t ws_size,
                              hipStream_t stream) {
    const float* X   = (const float*)d_in[0];
    const u32*   Yp  = (const u32*)d_in[1];
    const u32*   Zp  = (const u32*)d_in[2];
    const int*   Ys  = (const int*)d_in[3];
    const int*   Zs  = (const int*)d_in[4];
    const float* pa  = (const float*)d_in[5];
    const float* pb  = (const float*)d_in[6];
    const float* pc  = (const float*)d_in[7];
    const float* pd  = (const float*)d_in[8];
    const float* bias = (const float*)d_in[9];
    float* out = (float*)d_out;

    char* ws = (char*)d_ws;
    __hip_bfloat16* Wb = (__hip_bfloat16*)ws;                 // 2 MiB
    u16*            Xb = (u16*)(ws + (2u << 20));             // 32 MiB

    prep<<<8448, 256, 0, stream>>>(Yp, Zp, Ys, Zs, pa, pb, pc, pd, Wb,
                                   (const float4*)X, (ushort4*)Xb);
    gemm_bias<<<dim3(64, 8), 256, 0, stream>>>(Xb, (const u16*)Wb, bias, out);
}